// Round 13
// baseline (1087.140 us; speedup 1.0000x reference)
//
#include <hip/hip_runtime.h>
#include <math.h>

#define NN 50000
#define TT 16
#define DD 128
#define MT (NN * TT)
#define SCAN_B 1024
#define SCAN_NB ((NN + SCAN_B - 1) / SCAN_B)  // 49

typedef __attribute__((ext_vector_type(8))) short short8;
typedef __attribute__((ext_vector_type(4))) float f32x4;

// ---------- bf16 helpers ----------
static __device__ __forceinline__ unsigned short f2bf(float f) {
  unsigned u = __float_as_uint(f);
  u += 0x7FFFu + ((u >> 16) & 1u);  // RNE
  return (unsigned short)(u >> 16);
}
static __device__ __forceinline__ float bf_lo(unsigned v) {
  return __uint_as_float(v << 16);
}
static __device__ __forceinline__ float bf_hi(unsigned v) {
  return __uint_as_float(v & 0xffff0000u);
}

// ---------- graph preprocessing ----------

__global__ void k_init(int* __restrict__ deg, int* __restrict__ cur) {
  int i = blockIdx.x * blockDim.x + threadIdx.x;
  if (i < NN) { deg[i] = 1; cur[i] = 0; }  // self loop; fill cursor
}

__global__ void k_deg_count(const int* __restrict__ dst, int* __restrict__ deg, int e) {
  int i = blockIdx.x * blockDim.x + threadIdx.x;
  if (i < e) atomicAdd(&deg[dst[i]], 1);
}

// scan over (deg-1) -> rowptr (block-local) + dinv fold
__global__ __launch_bounds__(SCAN_B) void k_scan1(const int* __restrict__ deg,
                                                  int* __restrict__ rowptr,
                                                  int* __restrict__ bsums,
                                                  float* __restrict__ dinv) {
  __shared__ int sm[SCAN_B];
  int tid = threadIdx.x;
  int i = blockIdx.x * SCAN_B + tid;
  int d = (i < NN) ? deg[i] : 1;
  if (i < NN) dinv[i] = rsqrtf((float)d);
  int v = d - 1;
  sm[tid] = v;
  __syncthreads();
  for (int off = 1; off < SCAN_B; off <<= 1) {
    int t = (tid >= off) ? sm[tid - off] : 0;
    __syncthreads();
    sm[tid] += t;
    __syncthreads();
  }
  if (i < NN) rowptr[i] = sm[tid] - v;
  if (tid == SCAN_B - 1) bsums[blockIdx.x] = sm[tid];
}

__global__ void k_scan2(int* __restrict__ bsums) {
  __shared__ int sm[64];
  int tid = threadIdx.x;
  int v = (tid < SCAN_NB) ? bsums[tid] : 0;
  sm[tid] = v;
  __syncthreads();
  for (int off = 1; off < 64; off <<= 1) {
    int t = (tid >= off) ? sm[tid - off] : 0;
    __syncthreads();
    sm[tid] += t;
    __syncthreads();
  }
  if (tid < SCAN_NB) bsums[tid] = sm[tid] - v;
  if (tid == 63) bsums[SCAN_NB] = sm[63];
}

__global__ __launch_bounds__(SCAN_B) void k_scan3(int* __restrict__ rowptr,
                                                  const int* __restrict__ bsums) {
  int i = blockIdx.x * SCAN_B + threadIdx.x;
  if (i < NN) rowptr[i] += bsums[blockIdx.x];
  if (i == 0) rowptr[NN] = bsums[SCAN_NB];
}

__global__ void k_fill(const int* __restrict__ src, const int* __restrict__ dst,
                       const int* __restrict__ rowptr, int* __restrict__ cur,
                       int* __restrict__ col, int e) {
  int i = blockIdx.x * blockDim.x + threadIdx.x;
  if (i < e) {
    int d = dst[i];
    int slot = atomicAdd(&cur[d], 1);
    col[rowptr[d] + slot] = src[i];
  }
}

// W^T bf16 + bsum fold: Wt[n*128+k] = bf16(W[k*128+n]); block = n, thread = k
__global__ void k_wprep(const float* __restrict__ Wc, const float* __restrict__ Wl,
                        const float* __restrict__ bc, const float* __restrict__ bl,
                        unsigned short* __restrict__ Wct, unsigned short* __restrict__ Wlt,
                        float* __restrict__ bsum) {
  int n = blockIdx.x, k = threadIdx.x;
  Wct[n * 128 + k] = f2bf(Wc[k * 128 + n]);
  Wlt[n * 128 + k] = f2bf(Wl[k * 128 + n]);
  if (n == 0) bsum[k] = bc[k] + bl[k];
}

// ---------- GEMM-X (MFMA bf16, BM=64, 8 blocks/CU) -> int8 per-node-scaled Y ----------
// Wave w owns exactly node blockIdx*4+w (16 rows x 128 cols).
__global__ __launch_bounds__(256) void k_gemmx(
    const float* __restrict__ X, const unsigned short* __restrict__ Wct,
    const float* __restrict__ dinv, char* __restrict__ Yq, float* __restrict__ scaleN)
{
  __shared__ unsigned short sA[64 * 136];  // sA[r][k], pad 136
  const int tid = threadIdx.x;
  const long row0 = (long)blockIdx.x * 64;

  {
    const float4* xp = (const float4*)(X + row0 * 128);
    #pragma unroll
    for (int it = 0; it < 8; ++it) {
      float4 v = xp[it * 256 + tid];
      int q = it * 256 + tid;
      int r = q >> 5;
      int k = (q & 31) * 4;
      unsigned u0 = (unsigned)f2bf(v.x) | ((unsigned)f2bf(v.y) << 16);
      unsigned u1 = (unsigned)f2bf(v.z) | ((unsigned)f2bf(v.w) << 16);
      *(uint2*)&sA[r * 136 + k] = make_uint2(u0, u1);
    }
  }
  __syncthreads();

  const int w = tid >> 6, l = tid & 63;
  const int lr = l & 15;
  const int lk = (l >> 4) << 3;
  f32x4 acc[8];
  #pragma unroll
  for (int n = 0; n < 8; ++n) acc[n] = (f32x4){0.f, 0.f, 0.f, 0.f};

  #pragma unroll
  for (int kg = 0; kg < 4; ++kg) {
    int kb = kg * 32 + lk;
    short8 a = *(const short8*)&sA[(w * 16 + lr) * 136 + kb];
    #pragma unroll
    for (int n = 0; n < 8; ++n) {
      short8 b = *(const short8*)&Wct[(n * 16 + lr) * 128 + kb];
      // swapped operands: lane holds xrow = l&15, wcol = (l>>4)*4+reg
      acc[n] = __builtin_amdgcn_mfma_f32_16x16x32_bf16(b, a, acc[n], 0, 0, 0);
    }
  }

  const int wb = (l >> 4) * 4;
  const long rbase = row0 + w * 16;
  const int node = (int)(rbase >> 4);
  const long row = rbase + lr;
  float m = 0.f;
  #pragma unroll
  for (int n = 0; n < 8; ++n)
    #pragma unroll
    for (int r = 0; r < 4; ++r) m = fmaxf(m, fabsf(acc[n][r]));
  #pragma unroll
  for (int mask = 1; mask < 64; mask <<= 1)
    m = fmaxf(m, __shfl_xor(m, mask, 64));
  const float f = (m > 0.f) ? 127.f / m : 0.f;
  if (l == 0) scaleN[node] = m * dinv[node] * (1.f / 127.f);
  #pragma unroll
  for (int n = 0; n < 8; ++n) {
    int q0 = (int)__builtin_rintf(acc[n][0] * f);
    int q1 = (int)__builtin_rintf(acc[n][1] * f);
    int q2 = (int)__builtin_rintf(acc[n][2] * f);
    int q3 = (int)__builtin_rintf(acc[n][3] * f);
    unsigned u = (unsigned)(q0 & 255) | ((unsigned)(q1 & 255) << 8) |
                 ((unsigned)(q2 & 255) << 16) | ((unsigned)(q3 & 255) << 24);
    *(unsigned*)(Yq + row * 128 + n * 16 + wb) = u;
  }
}

// ---------- gather: one block per node, int8 rows (2KB coalesced), bsum folded in ----------
// aggT is t-major: [TT][NN][64] u32. thread tid: t = tid>>4, d = (tid&15)*8..+8
__global__ __launch_bounds__(256) void k_gatherN(
    const uint2* __restrict__ Yq,  // [NN][256] uint2 (8 int8 each)
    const float* __restrict__ scaleN,
    const int* __restrict__ col, const int* __restrict__ rowptr,
    const float* __restrict__ dinv, const float* __restrict__ bsum,
    unsigned* __restrict__ aggT)
{
  const int n = blockIdx.x;
  const int tid = threadIdx.x;
  float a0 = 0, a1 = 0, a2 = 0, a3 = 0, a4 = 0, a5 = 0, a6 = 0, a7 = 0;
  {
    uint2 v = Yq[(long)n * 256 + tid];  // self loop
    float ss = scaleN[n];
    a0 = fmaf((float)(signed char)(v.x),       ss, a0);
    a1 = fmaf((float)(signed char)(v.x >> 8),  ss, a1);
    a2 = fmaf((float)(signed char)(v.x >> 16), ss, a2);
    a3 = fmaf((float)(signed char)(v.x >> 24), ss, a3);
    a4 = fmaf((float)(signed char)(v.y),       ss, a4);
    a5 = fmaf((float)(signed char)(v.y >> 8),  ss, a5);
    a6 = fmaf((float)(signed char)(v.y >> 16), ss, a6);
    a7 = fmaf((float)(signed char)(v.y >> 24), ss, a7);
  }
  int j = rowptr[n];
  const int end = rowptr[n + 1];
  for (; j + 4 <= end; j += 4) {
    int s0 = col[j], s1 = col[j + 1], s2 = col[j + 2], s3 = col[j + 3];
    float c0 = scaleN[s0], c1 = scaleN[s1], c2 = scaleN[s2], c3 = scaleN[s3];
    uint2 v0 = Yq[(long)s0 * 256 + tid];
    uint2 v1 = Yq[(long)s1 * 256 + tid];
    uint2 v2 = Yq[(long)s2 * 256 + tid];
    uint2 v3 = Yq[(long)s3 * 256 + tid];
    a0 = fmaf((float)(signed char)(v0.x),       c0, a0);
    a1 = fmaf((float)(signed char)(v0.x >> 8),  c0, a1);
    a2 = fmaf((float)(signed char)(v0.x >> 16), c0, a2);
    a3 = fmaf((float)(signed char)(v0.x >> 24), c0, a3);
    a4 = fmaf((float)(signed char)(v0.y),       c0, a4);
    a5 = fmaf((float)(signed char)(v0.y >> 8),  c0, a5);
    a6 = fmaf((float)(signed char)(v0.y >> 16), c0, a6);
    a7 = fmaf((float)(signed char)(v0.y >> 24), c0, a7);
    a0 = fmaf((float)(signed char)(v1.x),       c1, a0);
    a1 = fmaf((float)(signed char)(v1.x >> 8),  c1, a1);
    a2 = fmaf((float)(signed char)(v1.x >> 16), c1, a2);
    a3 = fmaf((float)(signed char)(v1.x >> 24), c1, a3);
    a4 = fmaf((float)(signed char)(v1.y),       c1, a4);
    a5 = fmaf((float)(signed char)(v1.y >> 8),  c1, a5);
    a6 = fmaf((float)(signed char)(v1.y >> 16), c1, a6);
    a7 = fmaf((float)(signed char)(v1.y >> 24), c1, a7);
    a0 = fmaf((float)(signed char)(v2.x),       c2, a0);
    a1 = fmaf((float)(signed char)(v2.x >> 8),  c2, a1);
    a2 = fmaf((float)(signed char)(v2.x >> 16), c2, a2);
    a3 = fmaf((float)(signed char)(v2.x >> 24), c2, a3);
    a4 = fmaf((float)(signed char)(v2.y),       c2, a4);
    a5 = fmaf((float)(signed char)(v2.y >> 8),  c2, a5);
    a6 = fmaf((float)(signed char)(v2.y >> 16), c2, a6);
    a7 = fmaf((float)(signed char)(v2.y >> 24), c2, a7);
    a0 = fmaf((float)(signed char)(v3.x),       c3, a0);
    a1 = fmaf((float)(signed char)(v3.x >> 8),  c3, a1);
    a2 = fmaf((float)(signed char)(v3.x >> 16), c3, a2);
    a3 = fmaf((float)(signed char)(v3.x >> 24), c3, a3);
    a4 = fmaf((float)(signed char)(v3.y),       c3, a4);
    a5 = fmaf((float)(signed char)(v3.y >> 8),  c3, a5);
    a6 = fmaf((float)(signed char)(v3.y >> 16), c3, a6);
    a7 = fmaf((float)(signed char)(v3.y >> 24), c3, a7);
  }
  for (; j < end; ++j) {
    int s = col[j];
    float cs = scaleN[s];
    uint2 v = Yq[(long)s * 256 + tid];
    a0 = fmaf((float)(signed char)(v.x),       cs, a0);
    a1 = fmaf((float)(signed char)(v.x >> 8),  cs, a1);
    a2 = fmaf((float)(signed char)(v.x >> 16), cs, a2);
    a3 = fmaf((float)(signed char)(v.x >> 24), cs, a3);
    a4 = fmaf((float)(signed char)(v.y),       cs, a4);
    a5 = fmaf((float)(signed char)(v.y >> 8),  cs, a5);
    a6 = fmaf((float)(signed char)(v.y >> 16), cs, a6);
    a7 = fmaf((float)(signed char)(v.y >> 24), cs, a7);
  }
  const int t = tid >> 4, dq = tid & 15;
  const float di = dinv[n];
  const float4 b0 = *(const float4*)&bsum[dq * 8];
  const float4 b1 = *(const float4*)&bsum[dq * 8 + 4];
  // bsum folded into agg (added once per (t,d); recurrence uses agg directly)
  a0 = fmaf(a0, di, b0.x); a1 = fmaf(a1, di, b0.y);
  a2 = fmaf(a2, di, b0.z); a3 = fmaf(a3, di, b0.w);
  a4 = fmaf(a4, di, b1.x); a5 = fmaf(a5, di, b1.y);
  a6 = fmaf(a6, di, b1.z); a7 = fmaf(a7, di, b1.w);
  unsigned u0 = (unsigned)f2bf(a0) | ((unsigned)f2bf(a1) << 16);
  unsigned u1 = (unsigned)f2bf(a2) | ((unsigned)f2bf(a3) << 16);
  unsigned u2 = (unsigned)f2bf(a4) | ((unsigned)f2bf(a5) << 16);
  unsigned u3 = (unsigned)f2bf(a6) | ((unsigned)f2bf(a7) << 16);
  unsigned* ap = aggT + ((long)t * NN + n) * 64 + dq * 4;  // t-major
  __builtin_nontemporal_store(u0, ap);
  __builtin_nontemporal_store(u1, ap + 1);
  __builtin_nontemporal_store(u2, ap + 2);
  __builtin_nontemporal_store(u3, ap + 3);
}

// ---------- fused recurrence: all 16 t, 1 wave per 16 nodes, W in VGPRs ----------
__global__ __launch_bounds__(64) void k_rnn(
    const unsigned* __restrict__ aggT,       // [TT][NN][64] u32 (2 bf16, bsum included)
    const unsigned short* __restrict__ Wlt,  // [c][k] bf16 W_lin^T
    float* __restrict__ out)
{
  __shared__ unsigned sag[16 * 72];        // agg tile, row pad 72 u32
  __shared__ unsigned short hl[16 * 144];  // h tile bf16, row pad 144 u16
  const int l = threadIdx.x;
  const int lr = l & 15, lg = l >> 4;
  const long nbase = (long)blockIdx.x * 16;
  const long row = nbase + lr;

  // hoist all W_lin^T fragments into registers (32 x short8 = 128 VGPR)
  short8 wf[4][8];
  #pragma unroll
  for (int kg = 0; kg < 4; ++kg)
    #pragma unroll
    for (int n = 0; n < 8; ++n)
      wf[kg][n] = *(const short8*)&Wlt[(n * 16 + lr) * 128 + kg * 32 + lg * 8];

  uint4 g[4];
  // stage agg[t=0] (contiguous 4KB -> LDS)
  {
    const uint4* src = (const uint4*)(aggT + nbase * 64);
    #pragma unroll
    for (int i = 0; i < 4; ++i) g[i] = src[i * 64 + l];
    #pragma unroll
    for (int i = 0; i < 4; ++i) {
      int gi = (i * 64 + l) * 4;  // u32 index in [16][64]
      *(uint4*)&sag[(gi >> 6) * 72 + (gi & 63)] = g[i];
    }
  }
  // prefetch t=1
  {
    const uint4* src = (const uint4*)(aggT + ((long)NN + nbase) * 64);
    #pragma unroll
    for (int i = 0; i < 4; ++i) g[i] = src[i * 64 + l];
  }
  __syncthreads();
  // t=0: h0 = tanh(agg0)   (bsum already folded into agg)
  #pragma unroll
  for (int n = 0; n < 8; ++n) {
    uint2 ag = *(const uint2*)&sag[lr * 72 + n * 8 + lg * 2];
    float o0 = tanhf(bf_lo(ag.x));
    float o1 = tanhf(bf_hi(ag.x));
    float o2 = tanhf(bf_lo(ag.y));
    float o3 = tanhf(bf_hi(ag.y));
    *(float4*)(out + (row * TT) * 128 + n * 16 + lg * 4) = make_float4(o0, o1, o2, o3);
    unsigned u0 = (unsigned)f2bf(o0) | ((unsigned)f2bf(o1) << 16);
    unsigned u1 = (unsigned)f2bf(o2) | ((unsigned)f2bf(o3) << 16);
    *(uint2*)&hl[lr * 144 + n * 16 + lg * 4] = make_uint2(u0, u1);
  }
  __syncthreads();

  for (int t = 1; t < TT; ++t) {
    // write staged agg[t]
    #pragma unroll
    for (int i = 0; i < 4; ++i) {
      int gi = (i * 64 + l) * 4;
      *(uint4*)&sag[(gi >> 6) * 72 + (gi & 63)] = g[i];
    }
    // prefetch t+1
    if (t + 1 < TT) {
      const uint4* src = (const uint4*)(aggT + ((long)(t + 1) * NN + nbase) * 64);
      #pragma unroll
      for (int i = 0; i < 4; ++i) g[i] = src[i * 64 + l];
    }
    // B-fragments of h_{t-1}
    short8 bfr[4];
    #pragma unroll
    for (int kg = 0; kg < 4; ++kg)
      bfr[kg] = *(const short8*)&hl[lr * 144 + kg * 32 + lg * 8];
    __syncthreads();

    f32x4 acc[8];
    #pragma unroll
    for (int n = 0; n < 8; ++n) acc[n] = (f32x4){0.f, 0.f, 0.f, 0.f};
    #pragma unroll
    for (int kg = 0; kg < 4; ++kg) {
      #pragma unroll
      for (int n = 0; n < 8; ++n)
        acc[n] = __builtin_amdgcn_mfma_f32_16x16x32_bf16(wf[kg][n], bfr[kg], acc[n], 0, 0, 0);
    }
    #pragma unroll
    for (int n = 0; n < 8; ++n) {
      uint2 ag = *(const uint2*)&sag[lr * 72 + n * 8 + lg * 2];
      float o0 = tanhf(acc[n][0] + bf_lo(ag.x));
      float o1 = tanhf(acc[n][1] + bf_hi(ag.x));
      float o2 = tanhf(acc[n][2] + bf_lo(ag.y));
      float o3 = tanhf(acc[n][3] + bf_hi(ag.y));
      *(float4*)(out + (row * TT + t) * 128 + n * 16 + lg * 4) = make_float4(o0, o1, o2, o3);
      unsigned u0 = (unsigned)f2bf(o0) | ((unsigned)f2bf(o1) << 16);
      unsigned u1 = (unsigned)f2bf(o2) | ((unsigned)f2bf(o3) << 16);
      *(uint2*)&hl[lr * 144 + n * 16 + lg * 4] = make_uint2(u0, u1);
    }
    __syncthreads();
  }
}

extern "C" void kernel_launch(void* const* d_in, const int* in_sizes, int n_in,
                              void* d_out, int out_size, void* d_ws, size_t ws_size,
                              hipStream_t stream) {
  const float* x  = (const float*)d_in[0];
  const int*   ei = (const int*)d_in[1];
  const float* Wc = (const float*)d_in[2];
  const float* bc = (const float*)d_in[3];
  const float* Wl = (const float*)d_in[4];
  const float* bl = (const float*)d_in[5];
  float* out = (float*)d_out;
  const int E = in_sizes[1] / 2;
  const int* srcp = ei;
  const int* dstp = ei + E;

  char* w = (char*)d_ws;
  auto alloc = [&](size_t bytes) {
    char* p = w;
    w += (bytes + 255) & ~(size_t)255;
    return p;
  };
  int*            deg    = (int*)alloc(sizeof(int) * NN);
  float*          dinv   = (float*)alloc(sizeof(float) * NN);
  int*            rowptr = (int*)alloc(sizeof(int) * (NN + 1));
  int*            cur    = (int*)alloc(sizeof(int) * NN);
  int*            bsums  = (int*)alloc(sizeof(int) * (SCAN_NB + 1));
  int*            col    = (int*)alloc(sizeof(int) * (size_t)E);
  char*           Yq     = (char*)alloc((size_t)MT * DD);                         // 102.4 MB
  float*          scaleN = (float*)alloc(sizeof(float) * NN);
  unsigned*       aggT   = (unsigned*)alloc(sizeof(unsigned) * (size_t)MT * 64);  // 204.8 MB
  float*          bsum   = (float*)alloc(sizeof(float) * DD);
  unsigned short* Wct    = (unsigned short*)alloc(sizeof(unsigned short) * 128 * 128);
  unsigned short* Wlt    = (unsigned short*)alloc(sizeof(unsigned short) * 128 * 128);

  k_init<<<(NN + 255) / 256, 256, 0, stream>>>(deg, cur);
  k_deg_count<<<(E + 255) / 256, 256, 0, stream>>>(dstp, deg, E);
  k_scan1<<<SCAN_NB, SCAN_B, 0, stream>>>(deg, rowptr, bsums, dinv);
  k_scan2<<<1, 64, 0, stream>>>(bsums);
  k_scan3<<<SCAN_NB, SCAN_B, 0, stream>>>(rowptr, bsums);
  k_fill<<<(E + 255) / 256, 256, 0, stream>>>(srcp, dstp, rowptr, cur, col, E);
  k_wprep<<<128, 128, 0, stream>>>(Wc, Wl, bc, bl, Wct, Wlt, bsum);

  // Yq = int8((x @ Wc) scaled per node; dinv folded into scaleN); BM=64
  k_gemmx<<<MT / 64, 256, 0, stream>>>(x, Wct, dinv, Yq, scaleN);
  // single-pass gather: block per node, 2KB coalesced int8 row reads; bsum folded
  k_gatherN<<<NN, 256, 0, stream>>>((const uint2*)Yq, scaleN, col, rowptr, dinv, bsum, aggT);
  // fused recurrence: 1 wave per 16 nodes, W in VGPRs, agg staged via LDS
  k_rnn<<<NN / 16, 64, 0, stream>>>(aggT, Wlt, out);
}

// Round 14
// 1033.756 us; speedup vs baseline: 1.0516x; 1.0516x over previous
//
#include <hip/hip_runtime.h>
#include <math.h>

#define NN 50000
#define TT 16
#define DD 128
#define MT (NN * TT)
#define SCAN_B 1024
#define SCAN_NB ((NN + SCAN_B - 1) / SCAN_B)  // 49

typedef __attribute__((ext_vector_type(8))) short short8;
typedef __attribute__((ext_vector_type(4))) float f32x4;

// ---------- bf16 helpers ----------
static __device__ __forceinline__ unsigned short f2bf(float f) {
  unsigned u = __float_as_uint(f);
  u += 0x7FFFu + ((u >> 16) & 1u);  // RNE
  return (unsigned short)(u >> 16);
}
static __device__ __forceinline__ float bf_lo(unsigned v) {
  return __uint_as_float(v << 16);
}
static __device__ __forceinline__ float bf_hi(unsigned v) {
  return __uint_as_float(v & 0xffff0000u);
}

// ---------- graph preprocessing ----------

__global__ void k_init(int* __restrict__ deg, int* __restrict__ cur) {
  int i = blockIdx.x * blockDim.x + threadIdx.x;
  if (i < NN) { deg[i] = 1; cur[i] = 0; }  // self loop; fill cursor
}

__global__ void k_deg_count(const int* __restrict__ dst, int* __restrict__ deg, int e) {
  int i = blockIdx.x * blockDim.x + threadIdx.x;
  if (i < e) atomicAdd(&deg[dst[i]], 1);
}

// scan over (deg-1) -> rowptr (block-local) + dinv fold
__global__ __launch_bounds__(SCAN_B) void k_scan1(const int* __restrict__ deg,
                                                  int* __restrict__ rowptr,
                                                  int* __restrict__ bsums,
                                                  float* __restrict__ dinv) {
  __shared__ int sm[SCAN_B];
  int tid = threadIdx.x;
  int i = blockIdx.x * SCAN_B + tid;
  int d = (i < NN) ? deg[i] : 1;
  if (i < NN) dinv[i] = rsqrtf((float)d);
  int v = d - 1;
  sm[tid] = v;
  __syncthreads();
  for (int off = 1; off < SCAN_B; off <<= 1) {
    int t = (tid >= off) ? sm[tid - off] : 0;
    __syncthreads();
    sm[tid] += t;
    __syncthreads();
  }
  if (i < NN) rowptr[i] = sm[tid] - v;
  if (tid == SCAN_B - 1) bsums[blockIdx.x] = sm[tid];
}

__global__ void k_scan2(int* __restrict__ bsums) {
  __shared__ int sm[64];
  int tid = threadIdx.x;
  int v = (tid < SCAN_NB) ? bsums[tid] : 0;
  sm[tid] = v;
  __syncthreads();
  for (int off = 1; off < 64; off <<= 1) {
    int t = (tid >= off) ? sm[tid - off] : 0;
    __syncthreads();
    sm[tid] += t;
    __syncthreads();
  }
  if (tid < SCAN_NB) bsums[tid] = sm[tid] - v;
  if (tid == 63) bsums[SCAN_NB] = sm[63];
}

__global__ __launch_bounds__(SCAN_B) void k_scan3(int* __restrict__ rowptr,
                                                  const int* __restrict__ bsums) {
  int i = blockIdx.x * SCAN_B + threadIdx.x;
  if (i < NN) rowptr[i] += bsums[blockIdx.x];
  if (i == 0) rowptr[NN] = bsums[SCAN_NB];
}

__global__ void k_fill(const int* __restrict__ src, const int* __restrict__ dst,
                       const int* __restrict__ rowptr, int* __restrict__ cur,
                       int* __restrict__ col, int e) {
  int i = blockIdx.x * blockDim.x + threadIdx.x;
  if (i < e) {
    int d = dst[i];
    int slot = atomicAdd(&cur[d], 1);
    col[rowptr[d] + slot] = src[i];
  }
}

// W^T bf16 + bsum fold: Wt[n*128+k] = bf16(W[k*128+n]); block = n, thread = k
__global__ void k_wprep(const float* __restrict__ Wc, const float* __restrict__ Wl,
                        const float* __restrict__ bc, const float* __restrict__ bl,
                        unsigned short* __restrict__ Wct, unsigned short* __restrict__ Wlt,
                        float* __restrict__ bsum) {
  int n = blockIdx.x, k = threadIdx.x;
  Wct[n * 128 + k] = f2bf(Wc[k * 128 + n]);
  Wlt[n * 128 + k] = f2bf(Wl[k * 128 + n]);
  if (n == 0) bsum[k] = bc[k] + bl[k];
}

// ---------- GEMM-X (MFMA bf16, BM=128) -> int8 per-node-scaled Y ----------
// q = rint(acc * 127/m_node) (dinv cancels); scale_n = m_node * dinv_n / 127.
__global__ __launch_bounds__(256) void k_gemmx(
    const float* __restrict__ X, const unsigned short* __restrict__ Wct,
    const float* __restrict__ dinv, char* __restrict__ Yq, float* __restrict__ scaleN)
{
  __shared__ unsigned short sA[128 * 136];  // sA[r][k], pad 136
  const int tid = threadIdx.x;
  const long row0 = (long)blockIdx.x * 128;

  {
    const float4* xp = (const float4*)(X + row0 * 128);
    #pragma unroll
    for (int it = 0; it < 16; ++it) {
      float4 v = xp[it * 256 + tid];
      int q = it * 256 + tid;
      int r = q >> 5;
      int k = (q & 31) * 4;
      unsigned u0 = (unsigned)f2bf(v.x) | ((unsigned)f2bf(v.y) << 16);
      unsigned u1 = (unsigned)f2bf(v.z) | ((unsigned)f2bf(v.w) << 16);
      *(uint2*)&sA[r * 136 + k] = make_uint2(u0, u1);
    }
  }
  __syncthreads();

  const int w = tid >> 6, l = tid & 63;
  const int lr = l & 15;
  const int lk = (l >> 4) << 3;
  f32x4 acc[2][8];
  #pragma unroll
  for (int i = 0; i < 2; ++i)
    #pragma unroll
    for (int n = 0; n < 8; ++n) acc[i][n] = (f32x4){0.f, 0.f, 0.f, 0.f};

  #pragma unroll
  for (int kg = 0; kg < 4; ++kg) {
    int kb = kg * 32 + lk;
    short8 a0 = *(const short8*)&sA[(w * 32 + lr) * 136 + kb];
    short8 a1 = *(const short8*)&sA[(w * 32 + 16 + lr) * 136 + kb];
    #pragma unroll
    for (int n = 0; n < 8; ++n) {
      short8 b = *(const short8*)&Wct[(n * 16 + lr) * 128 + kb];
      acc[0][n] = __builtin_amdgcn_mfma_f32_16x16x32_bf16(b, a0, acc[0][n], 0, 0, 0);
      acc[1][n] = __builtin_amdgcn_mfma_f32_16x16x32_bf16(b, a1, acc[1][n], 0, 0, 0);
    }
  }

  const int wb = (l >> 4) * 4;
  #pragma unroll
  for (int i = 0; i < 2; ++i) {
    const long rbase = row0 + w * 32 + i * 16;
    const int node = (int)(rbase >> 4);
    const long row = rbase + lr;
    float m = 0.f;
    #pragma unroll
    for (int n = 0; n < 8; ++n)
      #pragma unroll
      for (int r = 0; r < 4; ++r) m = fmaxf(m, fabsf(acc[i][n][r]));
    #pragma unroll
    for (int mask = 1; mask < 64; mask <<= 1)
      m = fmaxf(m, __shfl_xor(m, mask, 64));
    const float f = (m > 0.f) ? 127.f / m : 0.f;
    if (l == 0) scaleN[node] = m * dinv[node] * (1.f / 127.f);
    #pragma unroll
    for (int n = 0; n < 8; ++n) {
      int q0 = (int)__builtin_rintf(acc[i][n][0] * f);
      int q1 = (int)__builtin_rintf(acc[i][n][1] * f);
      int q2 = (int)__builtin_rintf(acc[i][n][2] * f);
      int q3 = (int)__builtin_rintf(acc[i][n][3] * f);
      unsigned u = (unsigned)(q0 & 255) | ((unsigned)(q1 & 255) << 8) |
                   ((unsigned)(q2 & 255) << 16) | ((unsigned)(q3 & 255) << 24);
      *(unsigned*)(Yq + row * 128 + n * 16 + wb) = u;
    }
  }
}

// ---------- gather: one block per node, int8 rows (2KB coalesced), bsum folded in ----------
// aggT is t-major: [TT][NN][64] u32. thread tid: t = tid>>4, d = (tid&15)*8..+8
__global__ __launch_bounds__(256) void k_gatherN(
    const uint2* __restrict__ Yq,  // [NN][256] uint2 (8 int8 each)
    const float* __restrict__ scaleN,
    const int* __restrict__ col, const int* __restrict__ rowptr,
    const float* __restrict__ dinv, const float* __restrict__ bsum,
    unsigned* __restrict__ aggT)
{
  const int n = blockIdx.x;
  const int tid = threadIdx.x;
  float a0 = 0, a1 = 0, a2 = 0, a3 = 0, a4 = 0, a5 = 0, a6 = 0, a7 = 0;
  {
    uint2 v = Yq[(long)n * 256 + tid];  // self loop
    float ss = scaleN[n];
    a0 = fmaf((float)(signed char)(v.x),       ss, a0);
    a1 = fmaf((float)(signed char)(v.x >> 8),  ss, a1);
    a2 = fmaf((float)(signed char)(v.x >> 16), ss, a2);
    a3 = fmaf((float)(signed char)(v.x >> 24), ss, a3);
    a4 = fmaf((float)(signed char)(v.y),       ss, a4);
    a5 = fmaf((float)(signed char)(v.y >> 8),  ss, a5);
    a6 = fmaf((float)(signed char)(v.y >> 16), ss, a6);
    a7 = fmaf((float)(signed char)(v.y >> 24), ss, a7);
  }
  int j = rowptr[n];
  const int end = rowptr[n + 1];
  for (; j + 4 <= end; j += 4) {
    int s0 = col[j], s1 = col[j + 1], s2 = col[j + 2], s3 = col[j + 3];
    float c0 = scaleN[s0], c1 = scaleN[s1], c2 = scaleN[s2], c3 = scaleN[s3];
    uint2 v0 = Yq[(long)s0 * 256 + tid];
    uint2 v1 = Yq[(long)s1 * 256 + tid];
    uint2 v2 = Yq[(long)s2 * 256 + tid];
    uint2 v3 = Yq[(long)s3 * 256 + tid];
    a0 = fmaf((float)(signed char)(v0.x),       c0, a0);
    a1 = fmaf((float)(signed char)(v0.x >> 8),  c0, a1);
    a2 = fmaf((float)(signed char)(v0.x >> 16), c0, a2);
    a3 = fmaf((float)(signed char)(v0.x >> 24), c0, a3);
    a4 = fmaf((float)(signed char)(v0.y),       c0, a4);
    a5 = fmaf((float)(signed char)(v0.y >> 8),  c0, a5);
    a6 = fmaf((float)(signed char)(v0.y >> 16), c0, a6);
    a7 = fmaf((float)(signed char)(v0.y >> 24), c0, a7);
    a0 = fmaf((float)(signed char)(v1.x),       c1, a0);
    a1 = fmaf((float)(signed char)(v1.x >> 8),  c1, a1);
    a2 = fmaf((float)(signed char)(v1.x >> 16), c1, a2);
    a3 = fmaf((float)(signed char)(v1.x >> 24), c1, a3);
    a4 = fmaf((float)(signed char)(v1.y),       c1, a4);
    a5 = fmaf((float)(signed char)(v1.y >> 8),  c1, a5);
    a6 = fmaf((float)(signed char)(v1.y >> 16), c1, a6);
    a7 = fmaf((float)(signed char)(v1.y >> 24), c1, a7);
    a0 = fmaf((float)(signed char)(v2.x),       c2, a0);
    a1 = fmaf((float)(signed char)(v2.x >> 8),  c2, a1);
    a2 = fmaf((float)(signed char)(v2.x >> 16), c2, a2);
    a3 = fmaf((float)(signed char)(v2.x >> 24), c2, a3);
    a4 = fmaf((float)(signed char)(v2.y),       c2, a4);
    a5 = fmaf((float)(signed char)(v2.y >> 8),  c2, a5);
    a6 = fmaf((float)(signed char)(v2.y >> 16), c2, a6);
    a7 = fmaf((float)(signed char)(v2.y >> 24), c2, a7);
    a0 = fmaf((float)(signed char)(v3.x),       c3, a0);
    a1 = fmaf((float)(signed char)(v3.x >> 8),  c3, a1);
    a2 = fmaf((float)(signed char)(v3.x >> 16), c3, a2);
    a3 = fmaf((float)(signed char)(v3.x >> 24), c3, a3);
    a4 = fmaf((float)(signed char)(v3.y),       c3, a4);
    a5 = fmaf((float)(signed char)(v3.y >> 8),  c3, a5);
    a6 = fmaf((float)(signed char)(v3.y >> 16), c3, a6);
    a7 = fmaf((float)(signed char)(v3.y >> 24), c3, a7);
  }
  for (; j < end; ++j) {
    int s = col[j];
    float cs = scaleN[s];
    uint2 v = Yq[(long)s * 256 + tid];
    a0 = fmaf((float)(signed char)(v.x),       cs, a0);
    a1 = fmaf((float)(signed char)(v.x >> 8),  cs, a1);
    a2 = fmaf((float)(signed char)(v.x >> 16), cs, a2);
    a3 = fmaf((float)(signed char)(v.x >> 24), cs, a3);
    a4 = fmaf((float)(signed char)(v.y),       cs, a4);
    a5 = fmaf((float)(signed char)(v.y >> 8),  cs, a5);
    a6 = fmaf((float)(signed char)(v.y >> 16), cs, a6);
    a7 = fmaf((float)(signed char)(v.y >> 24), cs, a7);
  }
  const int t = tid >> 4, dq = tid & 15;
  const float di = dinv[n];
  const float4 b0 = *(const float4*)&bsum[dq * 8];
  const float4 b1 = *(const float4*)&bsum[dq * 8 + 4];
  a0 = fmaf(a0, di, b0.x); a1 = fmaf(a1, di, b0.y);
  a2 = fmaf(a2, di, b0.z); a3 = fmaf(a3, di, b0.w);
  a4 = fmaf(a4, di, b1.x); a5 = fmaf(a5, di, b1.y);
  a6 = fmaf(a6, di, b1.z); a7 = fmaf(a7, di, b1.w);
  unsigned u0 = (unsigned)f2bf(a0) | ((unsigned)f2bf(a1) << 16);
  unsigned u1 = (unsigned)f2bf(a2) | ((unsigned)f2bf(a3) << 16);
  unsigned u2 = (unsigned)f2bf(a4) | ((unsigned)f2bf(a5) << 16);
  unsigned u3 = (unsigned)f2bf(a6) | ((unsigned)f2bf(a7) << 16);
  unsigned* ap = aggT + ((long)t * NN + n) * 64 + dq * 4;  // t-major
  __builtin_nontemporal_store(u0, ap);
  __builtin_nontemporal_store(u1, ap + 1);
  __builtin_nontemporal_store(u2, ap + 2);
  __builtin_nontemporal_store(u3, ap + 3);
}

// ---------- fused recurrence: all 16 t, 1 wave per 16 nodes, W in VGPRs ----------
// out writes staged via LDS -> 512B-contiguous store requests (16 req/step vs 128).
__global__ __launch_bounds__(64) void k_rnn(
    const unsigned* __restrict__ aggT,       // [TT][NN][64] u32 (2 bf16, bsum included)
    const unsigned short* __restrict__ Wlt,  // [c][k] bf16 W_lin^T
    float* __restrict__ out)
{
  __shared__ unsigned sag[16 * 72];        // agg tile, row pad 72 u32
  __shared__ unsigned short hl[16 * 144];  // h tile bf16, row pad 144 u16
  __shared__ float ob[16 * 132];           // out tile fp32, row pad 132
  const int l = threadIdx.x;
  const int lr = l & 15, lg = l >> 4;
  const long nbase = (long)blockIdx.x * 16;

  // hoist all W_lin^T fragments into registers (32 x short8 = 128 VGPR)
  short8 wf[4][8];
  #pragma unroll
  for (int kg = 0; kg < 4; ++kg)
    #pragma unroll
    for (int n = 0; n < 8; ++n)
      wf[kg][n] = *(const short8*)&Wlt[(n * 16 + lr) * 128 + kg * 32 + lg * 8];

  uint4 g[4];
  // stage agg[t=0] (contiguous 4KB -> LDS)
  {
    const uint4* src = (const uint4*)(aggT + nbase * 64);
    #pragma unroll
    for (int i = 0; i < 4; ++i) g[i] = src[i * 64 + l];
    #pragma unroll
    for (int i = 0; i < 4; ++i) {
      int gi = (i * 64 + l) * 4;  // u32 index in [16][64]
      *(uint4*)&sag[(gi >> 6) * 72 + (gi & 63)] = g[i];
    }
  }
  // prefetch t=1
  {
    const uint4* src = (const uint4*)(aggT + ((long)NN + nbase) * 64);
    #pragma unroll
    for (int i = 0; i < 4; ++i) g[i] = src[i * 64 + l];
  }
  __syncthreads();
  // t=0: h0 = tanh(agg0)   (bsum already folded into agg)
  #pragma unroll
  for (int n = 0; n < 8; ++n) {
    uint2 ag = *(const uint2*)&sag[lr * 72 + n * 8 + lg * 2];
    float o0 = tanhf(bf_lo(ag.x));
    float o1 = tanhf(bf_hi(ag.x));
    float o2 = tanhf(bf_lo(ag.y));
    float o3 = tanhf(bf_hi(ag.y));
    *(float4*)&ob[lr * 132 + n * 16 + lg * 4] = make_float4(o0, o1, o2, o3);
    unsigned u0 = (unsigned)f2bf(o0) | ((unsigned)f2bf(o1) << 16);
    unsigned u1 = (unsigned)f2bf(o2) | ((unsigned)f2bf(o3) << 16);
    *(uint2*)&hl[lr * 144 + n * 16 + lg * 4] = make_uint2(u0, u1);
  }
  __syncthreads();
  // coalesced out write for t=0: 2 rows per iteration, 512B contiguous per row
  #pragma unroll
  for (int i = 0; i < 8; ++i) {
    int r2 = i * 2 + (l >> 5);
    int c = (l & 31) * 4;
    float4 v = *(const float4*)&ob[r2 * 132 + c];
    *(float4*)(out + ((nbase + r2) * TT) * 128 + c) = v;
  }

  for (int t = 1; t < TT; ++t) {
    // write staged agg[t]
    #pragma unroll
    for (int i = 0; i < 4; ++i) {
      int gi = (i * 64 + l) * 4;
      *(uint4*)&sag[(gi >> 6) * 72 + (gi & 63)] = g[i];
    }
    // prefetch t+1
    if (t + 1 < TT) {
      const uint4* src = (const uint4*)(aggT + ((long)(t + 1) * NN + nbase) * 64);
      #pragma unroll
      for (int i = 0; i < 4; ++i) g[i] = src[i * 64 + l];
    }
    // B-fragments of h_{t-1}
    short8 bfr[4];
    #pragma unroll
    for (int kg = 0; kg < 4; ++kg)
      bfr[kg] = *(const short8*)&hl[lr * 144 + kg * 32 + lg * 8];
    __syncthreads();

    f32x4 acc[8];
    #pragma unroll
    for (int n = 0; n < 8; ++n) acc[n] = (f32x4){0.f, 0.f, 0.f, 0.f};
    #pragma unroll
    for (int kg = 0; kg < 4; ++kg) {
      #pragma unroll
      for (int n = 0; n < 8; ++n)
        acc[n] = __builtin_amdgcn_mfma_f32_16x16x32_bf16(wf[kg][n], bfr[kg], acc[n], 0, 0, 0);
    }
    #pragma unroll
    for (int n = 0; n < 8; ++n) {
      uint2 ag = *(const uint2*)&sag[lr * 72 + n * 8 + lg * 2];
      float o0 = tanhf(acc[n][0] + bf_lo(ag.x));
      float o1 = tanhf(acc[n][1] + bf_hi(ag.x));
      float o2 = tanhf(acc[n][2] + bf_lo(ag.y));
      float o3 = tanhf(acc[n][3] + bf_hi(ag.y));
      *(float4*)&ob[lr * 132 + n * 16 + lg * 4] = make_float4(o0, o1, o2, o3);
      unsigned u0 = (unsigned)f2bf(o0) | ((unsigned)f2bf(o1) << 16);
      unsigned u1 = (unsigned)f2bf(o2) | ((unsigned)f2bf(o3) << 16);
      *(uint2*)&hl[lr * 144 + n * 16 + lg * 4] = make_uint2(u0, u1);
    }
    __syncthreads();
    // coalesced out write: 2 rows / iter, 512B contiguous requests
    #pragma unroll
    for (int i = 0; i < 8; ++i) {
      int r2 = i * 2 + (l >> 5);
      int c = (l & 31) * 4;
      float4 v = *(const float4*)&ob[r2 * 132 + c];
      *(float4*)(out + ((nbase + r2) * TT + t) * 128 + c) = v;
    }
  }
}

extern "C" void kernel_launch(void* const* d_in, const int* in_sizes, int n_in,
                              void* d_out, int out_size, void* d_ws, size_t ws_size,
                              hipStream_t stream) {
  const float* x  = (const float*)d_in[0];
  const int*   ei = (const int*)d_in[1];
  const float* Wc = (const float*)d_in[2];
  const float* bc = (const float*)d_in[3];
  const float* Wl = (const float*)d_in[4];
  const float* bl = (const float*)d_in[5];
  float* out = (float*)d_out;
  const int E = in_sizes[1] / 2;
  const int* srcp = ei;
  const int* dstp = ei + E;

  char* w = (char*)d_ws;
  auto alloc = [&](size_t bytes) {
    char* p = w;
    w += (bytes + 255) & ~(size_t)255;
    return p;
  };
  int*            deg    = (int*)alloc(sizeof(int) * NN);
  float*          dinv   = (float*)alloc(sizeof(float) * NN);
  int*            rowptr = (int*)alloc(sizeof(int) * (NN + 1));
  int*            cur    = (int*)alloc(sizeof(int) * NN);
  int*            bsums  = (int*)alloc(sizeof(int) * (SCAN_NB + 1));
  int*            col    = (int*)alloc(sizeof(int) * (size_t)E);
  char*           Yq     = (char*)alloc((size_t)MT * DD);                         // 102.4 MB
  float*          scaleN = (float*)alloc(sizeof(float) * NN);
  unsigned*       aggT   = (unsigned*)alloc(sizeof(unsigned) * (size_t)MT * 64);  // 204.8 MB
  float*          bsum   = (float*)alloc(sizeof(float) * DD);
  unsigned short* Wct    = (unsigned short*)alloc(sizeof(unsigned short) * 128 * 128);
  unsigned short* Wlt    = (unsigned short*)alloc(sizeof(unsigned short) * 128 * 128);

  k_init<<<(NN + 255) / 256, 256, 0, stream>>>(deg, cur);
  k_deg_count<<<(E + 255) / 256, 256, 0, stream>>>(dstp, deg, E);
  k_scan1<<<SCAN_NB, SCAN_B, 0, stream>>>(deg, rowptr, bsums, dinv);
  k_scan2<<<1, 64, 0, stream>>>(bsums);
  k_scan3<<<SCAN_NB, SCAN_B, 0, stream>>>(rowptr, bsums);
  k_fill<<<(E + 255) / 256, 256, 0, stream>>>(srcp, dstp, rowptr, cur, col, E);
  k_wprep<<<128, 128, 0, stream>>>(Wc, Wl, bc, bl, Wct, Wlt, bsum);

  // Yq = int8((x @ Wc) scaled per node; dinv folded into scaleN); BM=128
  k_gemmx<<<MT / 128, 256, 0, stream>>>(x, Wct, dinv, Yq, scaleN);
  // single-pass gather: block per node, 2KB coalesced int8 row reads; bsum folded
  k_gatherN<<<NN, 256, 0, stream>>>((const uint2*)Yq, scaleN, col, rowptr, dinv, bsum, aggT);
  // fused recurrence: 1 wave per 16 nodes, W in VGPRs, LDS-staged coalesced out
  k_rnn<<<NN / 16, 64, 0, stream>>>(aggT, Wlt, out);
}